// Round 9
// baseline (367.273 us; speedup 1.0000x reference)
//
#include <hip/hip_runtime.h>
#include <hip/hip_bf16.h>

// TrittentionCube on MI355X. B=1, P=256, D=512, N=8, H=64. Round 9:
//  - tri_attn no longer contracts W_V: it writes S'[n][r][(h,g)] = S/Z (bf16)
//    to Sbuf; a new 32-block MFMA z_kern does z = S' @ W_V_flat with W_V
//    staged in LDS (W_V read 4x total instead of 2048x).
//  - E-loop: wave-uniform 3-case masking (interior tiles = plain exp).
// Input dtype (bf16 vs fp32) via runtime probe (evidence says fp32);
// ws use ~21 MB (Sbuf 16.8 MB) — revert to r8 layout if this round fails.

typedef __hip_bfloat16 bf16;
typedef __attribute__((ext_vector_type(8))) short short8;
typedef __attribute__((ext_vector_type(4))) short s16x4;
typedef __attribute__((ext_vector_type(4))) float floatx4;

__device__ __forceinline__ float ldf(const float* p){ return *p; }
__device__ __forceinline__ float ldf(const bf16* p){ return __bfloat162float(*p); }
__device__ __forceinline__ void  stf(float* p, float v){ *p = v; }
__device__ __forceinline__ void  stf(bf16*  p, float v){ *p = __float2bfloat16(v); }

__device__ __forceinline__ floatx4 mfma16(short8 a, short8 b, floatx4 c){
  return __builtin_amdgcn_mfma_f32_16x16x32_bf16(a, b, c, 0, 0, 0);
}
__device__ __forceinline__ short8 ld_g8(const bf16* p){
  return *reinterpret_cast<const short8*>(p);
}
__device__ __forceinline__ short bfs(float x){
  bf16 v = __float2bfloat16(x);
  return *reinterpret_cast<short*>(&v);
}

// Input-dtype probe: flag=1 if bf16, 0 if fp32.
__global__ void dtype_probe(const unsigned* __restrict__ x, int* __restrict__ flag)
{
  int t = threadIdx.x;              // 64 threads
  int cnt = 0;
  #pragma unroll
  for (int k = 0; k < 4; k++) {
    unsigned w = x[t*4 + k];
    unsigned lo = w & 0xFFFFu;
    unsigned e  = (lo >> 7) & 0xFFu;
    if (lo == 0u || (e >= 90u && e <= 145u)) cnt++;
  }
  #pragma unroll
  for (int off = 32; off; off >>= 1) cnt += __shfl_down(cnt, off);
  if (t == 0) *flag = (cnt >= 160) ? 1 : 0;
}

// Fused 5-projection kernel: t_j[p,n,h] = x @ W_j[n] + b_j[n].
// j<3: [p][n*64+h]; j>=3: transposed [n][h][p] (tdT/teT for MFMA B-frags).
template<typename TI>
__global__ __launch_bounds__(256) void proj_kern(
    const int* __restrict__ gate, int want, const TI* __restrict__ x,
    const TI* __restrict__ W0, const TI* __restrict__ b0,
    const TI* __restrict__ W1, const TI* __restrict__ b1,
    const TI* __restrict__ W2, const TI* __restrict__ b2,
    const TI* __restrict__ W3, const TI* __restrict__ b3,
    const TI* __restrict__ W4, const TI* __restrict__ b4,
    bf16* __restrict__ tproj)
{
  if (*gate != want) return;
  const TI* Ws[5] = {W0, W1, W2, W3, W4};
  const TI* bs[5] = {b0, b1, b2, b3, b4};
  const int bz = blockIdx.z, j = bz >> 3, n = bz & 7;
  const TI* B    = Ws[j] + (size_t)n * 32768;
  const TI* bias = bs[j] + n * 64;
  bf16* out = tproj + (size_t)j * 131072;
  const int m0 = blockIdx.y * 64;
  __shared__ float As[16][68];
  __shared__ float Bs[16][68];
  const int t = threadIdx.x, tx = t & 15, ty = t >> 4;
  float acc[4][4] = {};
  for (int k0 = 0; k0 < 512; k0 += 16) {
    { int m = t >> 2, kk = (t & 3) * 4;
      const TI* ap = x + (size_t)(m0 + m) * 512 + (k0 + kk);
      float a0 = ldf(ap+0), a1 = ldf(ap+1), a2 = ldf(ap+2), a3 = ldf(ap+3);
      As[kk+0][m] = a0; As[kk+1][m] = a1; As[kk+2][m] = a2; As[kk+3][m] = a3; }
    { int kk = t >> 4, nn = (t & 15) * 4;
      const TI* bp = B + (size_t)(k0 + kk) * 64 + nn;
      Bs[kk][nn+0] = ldf(bp+0); Bs[kk][nn+1] = ldf(bp+1);
      Bs[kk][nn+2] = ldf(bp+2); Bs[kk][nn+3] = ldf(bp+3); }
    __syncthreads();
    #pragma unroll
    for (int kk = 0; kk < 16; kk++) {
      float4 a4 = *reinterpret_cast<const float4*>(&As[kk][ty*4]);
      float4 b4 = *reinterpret_cast<const float4*>(&Bs[kk][tx*4]);
      float av[4] = {a4.x,a4.y,a4.z,a4.w}, bv[4] = {b4.x,b4.y,b4.z,b4.w};
      #pragma unroll
      for (int im = 0; im < 4; im++)
        #pragma unroll
        for (int in = 0; in < 4; in++) acc[im][in] += av[im] * bv[in];
    }
    __syncthreads();
  }
  #pragma unroll
  for (int im = 0; im < 4; im++)
    #pragma unroll
    for (int in = 0; in < 4; in++) {
      float v = acc[im][in] + ldf(bias + tx*4 + in);
      int p = m0 + ty*4 + im, h = tx*4 + in;
      if (j < 3) out[(size_t)p * 512 + n*64 + h] = __float2bfloat16(v);
      else       out[(size_t)n * 16384 + (size_t)h * 256 + p] = __float2bfloat16(v);
    }
}

// MFMA s1t: s1t[r][(i,j)] = sum_{n,k} tc[r][(n,k)] * W_K[n][i][j][k].
template<typename TW>
__global__ __launch_bounds__(256) void s1t_mfma(
    const int* __restrict__ gate, int want,
    const bf16* __restrict__ tc, const TW* __restrict__ WK, bf16* __restrict__ s1t)
{
  if (*gate != want) return;
  const int i = blockIdx.x;
  const int t = threadIdx.x, wid = t >> 6, lane = t & 63, quad = lane >> 4, l16 = lane & 15;
  const int rw = blockIdx.y * 64 + wid * 16;
  floatx4 acc[4];
  #pragma unroll
  for (int jt = 0; jt < 4; jt++) acc[jt] = (floatx4){0.f, 0.f, 0.f, 0.f};
  for (int kc = 0; kc < 16; kc++) {
    short8 af = ld_g8(tc + (size_t)(rw + l16) * 512 + kc*32 + quad*8);
    const int n = kc >> 1, kk = (kc & 1) * 32 + quad * 8;
    #pragma unroll
    for (int jt = 0; jt < 4; jt++) {
      const TW* bp = WK + ((size_t)(n*64 + i) * 64 + jt*16 + l16) * 64 + kk;
      short8 bf;
      if constexpr (sizeof(TW) == 2) {
        bf = ld_g8((const bf16*)bp);
      } else {
        float4 x0 = *reinterpret_cast<const float4*>(bp);
        float4 x1 = *reinterpret_cast<const float4*>(bp + 4);
        bf[0]=bfs(x0.x); bf[1]=bfs(x0.y); bf[2]=bfs(x0.z); bf[3]=bfs(x0.w);
        bf[4]=bfs(x1.x); bf[5]=bfs(x1.y); bf[6]=bfs(x1.z); bf[7]=bfs(x1.w);
      }
      acc[jt] = mfma16(af, bf, acc[jt]);
    }
  }
  #pragma unroll
  for (int jt = 0; jt < 4; jt++)
    #pragma unroll
    for (int reg = 0; reg < 4; reg++)
      s1t[(size_t)(rw + quad*4 + reg) * 4096 + i*64 + jt*16 + l16] =
          __float2bfloat16(acc[jt][reg]);
}

// Generic 64x64-tile GEMM (final out only).
template<typename TA, typename TB, typename TC, bool BIAS>
__global__ __launch_bounds__(256) void gemm_tile(
    const int* __restrict__ gate, int want,
    const TA* __restrict__ A, const TB* __restrict__ B, TC* __restrict__ C,
    const TB* __restrict__ bias,
    int Ncols, int K, int lda, int ldc)
{
  if (*gate != want) return;
  const int m0 = blockIdx.y * 64, n0 = blockIdx.x * 64;
  __shared__ float As[16][68];
  __shared__ float Bs[16][68];
  const int t = threadIdx.x, tx = t & 15, ty = t >> 4;
  float acc[4][4] = {};
  for (int k0 = 0; k0 < K; k0 += 16) {
    { int m = t >> 2, kk = (t & 3) * 4;
      const TA* ap = A + (size_t)(m0 + m) * lda + (k0 + kk);
      float a0 = ldf(ap+0), a1 = ldf(ap+1), a2 = ldf(ap+2), a3 = ldf(ap+3);
      As[kk+0][m] = a0; As[kk+1][m] = a1; As[kk+2][m] = a2; As[kk+3][m] = a3; }
    { int kk = t >> 4, nn = (t & 15) * 4;
      const TB* bp = B + (size_t)(k0 + kk) * Ncols + (n0 + nn);
      Bs[kk][nn+0] = ldf(bp+0); Bs[kk][nn+1] = ldf(bp+1);
      Bs[kk][nn+2] = ldf(bp+2); Bs[kk][nn+3] = ldf(bp+3); }
    __syncthreads();
    #pragma unroll
    for (int kk = 0; kk < 16; kk++) {
      float4 a4 = *reinterpret_cast<const float4*>(&As[kk][ty*4]);
      float4 b4 = *reinterpret_cast<const float4*>(&Bs[kk][tx*4]);
      float av[4] = {a4.x,a4.y,a4.z,a4.w}, bv[4] = {b4.x,b4.y,b4.z,b4.w};
      #pragma unroll
      for (int im = 0; im < 4; im++)
        #pragma unroll
        for (int in = 0; in < 4; in++) acc[im][in] += av[im] * bv[in];
    }
    __syncthreads();
  }
  #pragma unroll
  for (int im = 0; im < 4; im++) {
    TC* cp = C + (size_t)(m0 + ty*4 + im) * ldc + n0 + tx*4;
    #pragma unroll
    for (int in = 0; in < 4; in++) {
      float v = acc[im][in];
      if constexpr (BIAS) v += ldf(bias + n0 + tx*4 + in);
      stf(cp + in, v);
    }
  }
}

// tbs[q][j] = (1/64) * sum_n tb[q][n][j]  -> bf16 [q][64]
__global__ __launch_bounds__(256) void tbs_kern(const bf16* __restrict__ tb,
                                                bf16* __restrict__ tbsbf)
{
  int t = blockIdx.x * 256 + threadIdx.x;
  int q = t >> 6, j = t & 63;
  float s = 0.f;
  #pragma unroll
  for (int n = 0; n < 8; n++) s += ldf(tb + q*512 + n*64 + j);
  tbsbf[t] = __float2bfloat16(s * 0.015625f);
}

// Per-(n,r) MFMA attention -> S' = S/Z written to Sbuf (no W_V here).
// LDS 53760 B: [0,34816) c [256][136 B] / Tt [64][528 B]; [34816,53248) Ew
// [64][72 B] x4 waves; [53248,53760) scr. p-tiles interleaved (i = pt*4+wid).
// dtype-independent: single ungated launch.
__global__ __launch_bounds__(256) void tri_attn(
    const bf16* __restrict__ ta,     // [p][n*64+h]
    const bf16* __restrict__ tbsbf,  // [q][64]
    const bf16* __restrict__ s1t,    // [r][i*64+j]
    const bf16* __restrict__ tdT,    // [n][h][p]
    const bf16* __restrict__ teT,    // [n][g][q]
    bf16* __restrict__ Sbuf)         // [n][r][h*64+g]
{
  __shared__ __align__(16) char smb[53760];
  const int bx = blockIdx.x;
  const int n = bx & 7;               // n -> XCD affinity
  const int r = 255 - (bx >> 3);      // big-r first
  const int t = threadIdx.x;
  const int wid = t >> 6, lane = t & 63, quad = lane >> 4, l16 = lane & 15;
  bf16* srow = Sbuf + (size_t)n * 1048576 + (size_t)r * 4096;
  if (r < 2) {                        // no valid (p<q<r): S' = 0 (z=0 downstream)
    short8 zz = (short8){0,0,0,0,0,0,0,0};
    reinterpret_cast<short8*>(srow)[t]       = zz;
    reinterpret_cast<short8*>(srow)[t + 256] = zz;
    return;
  }

  // ---- Phase 1: c[q][i] = tbs[q,:]·s1t[r][i,:]  (rows q<1 or q>=r zeroed)
  {
    const bf16* s1r = s1t + (size_t)r * 4096;
    short8 bfr[4][2];
    #pragma unroll
    for (int it = 0; it < 4; it++)
      #pragma unroll
      for (int kc = 0; kc < 2; kc++)
        bfr[it][kc] = ld_g8(s1r + (it*16 + l16)*64 + kc*32 + quad*8);
    #pragma unroll
    for (int qt = 0; qt < 4; qt++) {
      const int q0 = wid * 64 + qt * 16;
      short8 af0 = ld_g8(tbsbf + (q0 + l16)*64 + quad*8);
      short8 af1 = ld_g8(tbsbf + (q0 + l16)*64 + 32 + quad*8);
      #pragma unroll
      for (int it = 0; it < 4; it++) {
        floatx4 acc = {0.f, 0.f, 0.f, 0.f};
        acc = mfma16(af0, bfr[it][0], acc);
        acc = mfma16(af1, bfr[it][1], acc);
        #pragma unroll
        for (int reg = 0; reg < 4; reg++) {
          int q = q0 + quad*4 + reg;
          float v = (q >= 1 && q < r) ? acc[reg] : 0.f;
          *reinterpret_cast<bf16*>(smb + q*136 + (it*16 + l16)*2) = __float2bfloat16(v);
        }
      }
    }
  }
  // ta A-fragments for interleaved p-tiles: tile base (pt*4+wid)*16
  short8 taf[4][2];
  #pragma unroll
  for (int pt = 0; pt < 4; pt++)
    #pragma unroll
    for (int kc = 0; kc < 2; kc++)
      taf[pt][kc] = ld_g8(ta + (size_t)((pt*4 + wid)*16 + l16)*512 + n*64
                             + kc*32 + quad*8);
  __syncthreads();                    // c visible

  // ---- Main loop: E chunk + T accumulate; 3-case wave-uniform masking
  floatx4 Tacc[4][4];
  #pragma unroll
  for (int pt = 0; pt < 4; pt++)
    #pragma unroll
    for (int gt = 0; gt < 4; gt++) Tacc[pt][gt] = (floatx4){0.f, 0.f, 0.f, 0.f};
  float Zp = 0.f;
  char* EwB = smb + 34816 + wid * 4608;          // [64][72 B] bf16 per wave
  const int nch = ((r - 1) >> 5) + 1;
  for (int ch = 0; ch < nch; ch++) {
    const int qc = ch * 32;
    if (qc + 31 <= wid * 16) continue;  // all this wave's tiles dead
    short8 cfr[2][2];
    #pragma unroll
    for (int qt2 = 0; qt2 < 2; qt2++)
      #pragma unroll
      for (int kc = 0; kc < 2; kc++)
        cfr[qt2][kc] = *reinterpret_cast<const short8*>(
            smb + (qc + qt2*16 + l16)*136 + (kc*32 + quad*8)*2);
    #pragma unroll
    for (int pt = 0; pt < 4; pt++) {
      const int ptb = (pt*4 + wid) * 16;
      if (ptb < qc + 31) {            // wave-uniform: tile has live (p,q)
        #pragma unroll
        for (int qt2 = 0; qt2 < 2; qt2++) {
          const int qh = qc + qt2*16;
          char* erow0 = EwB + (pt*16 + quad*4)*72 + (qt2*16 + l16)*2;
          if (qh + 15 <= ptb) {                   // fully-masked half-tile
            #pragma unroll
            for (int reg = 0; reg < 4; reg++)
              *reinterpret_cast<bf16*>(erow0 + reg*72) = __float2bfloat16(0.f);
          } else {
            floatx4 acc = {0.f, 0.f, 0.f, 0.f};
            acc = mfma16(taf[pt][0], cfr[qt2][0], acc);
            acc = mfma16(taf[pt][1], cfr[qt2][1], acc);
            if (qh >= ptb + 16 && qh + 15 < r) {  // interior: no per-lane mask
              #pragma unroll
              for (int reg = 0; reg < 4; reg++) {
                float e = __expf(acc[reg]);
                Zp += e;
                *reinterpret_cast<bf16*>(erow0 + reg*72) = __float2bfloat16(e);
              }
            } else {                              // diagonal / last chunk
              #pragma unroll
              for (int reg = 0; reg < 4; reg++) {
                int p = ptb + quad*4 + reg;
                int q = qh + l16;
                float e = (p < q && q < r) ? __expf(acc[reg]) : 0.f;
                Zp += e;
                *reinterpret_cast<bf16*>(erow0 + reg*72) = __float2bfloat16(e);
              }
            }
          }
        }
      }
    }
    short8 tef[4];
    #pragma unroll
    for (int gt = 0; gt < 4; gt++)
      tef[gt] = ld_g8(teT + (size_t)n*16384 + (gt*16 + l16)*256 + qc + quad*8);
    #pragma unroll
    for (int pt = 0; pt < 4; pt++) {
      if ((pt*4 + wid)*16 < qc + 31) {
        short8 ef = *reinterpret_cast<const short8*>(EwB + (pt*16 + l16)*72 + quad*16);
        #pragma unroll
        for (int gt = 0; gt < 4; gt++)
          Tacc[pt][gt] = mfma16(ef, tef[gt], Tacc[pt][gt]);
      }
    }
  }
  #pragma unroll
  for (int off = 32; off; off >>= 1) Zp += __shfl_down(Zp, off);
  float* scr = reinterpret_cast<float*>(smb + 53248);
  if (lane == 0) scr[wid] = Zp;
  __syncthreads();                    // closes all c reads; Z visible
  const float rinv = 1.f / (scr[0] + scr[1] + scr[2] + scr[3]);

  // ---- Tt[g][p] (bf16, stride 528 B) over dead c region
  #pragma unroll
  for (int pt = 0; pt < 4; pt++)
    #pragma unroll
    for (int gt = 0; gt < 4; gt++)
      #pragma unroll
      for (int reg = 0; reg < 4; reg++) {
        int g = gt*16 + l16;
        int p = (pt*4 + wid)*16 + quad*4 + reg;
        *reinterpret_cast<bf16*>(smb + g*528 + p*2) = __float2bfloat16(Tacc[pt][gt][reg]);
      }
  __syncthreads();

  // ---- S[g][h] = T^T·tdT (K=256); wave w: g-rows [16w,16w+16);
  //      store S' = S*rinv to Sbuf[h*64+g] (z_kern's A-operand layout)
  {
    short8 Taf[8];
    #pragma unroll
    for (int kc = 0; kc < 8; kc++)
      Taf[kc] = *reinterpret_cast<const short8*>(
          smb + (wid*16 + l16)*528 + (kc*32 + quad*8)*2);
    #pragma unroll
    for (int ht = 0; ht < 4; ht++) {
      floatx4 acc = {0.f, 0.f, 0.f, 0.f};
      #pragma unroll
      for (int kc = 0; kc < 8; kc++) {
        short8 bfragd = ld_g8(tdT + (size_t)n*16384 + (ht*16 + l16)*256 + kc*32 + quad*8);
        acc = mfma16(Taf[kc], bfragd, acc);
      }
      #pragma unroll
      for (int reg = 0; reg < 4; reg++) {
        int g = wid*16 + quad*4 + reg, h = ht*16 + l16;
        srow[h*64 + g] = __float2bfloat16(acc[reg] * rinv);
      }
    }
  }
}

// z_kern: z[r, n*64+f] = sum_k S'[n][r][k] * WVflat[n][k][f]  (K = 4096).
// Grid (rt=4, n=8); wave w: 16 r-rows. W_V chunk staged in LDS [k=32][f=64]
// (stride 136 B, conflict-free reads); A-frags straight from Sbuf (contiguous).
template<typename TW>
__global__ __launch_bounds__(256) void z_kern(
    const int* __restrict__ gate, int want,
    const bf16* __restrict__ Sbuf, const TW* __restrict__ WV, bf16* __restrict__ zbb)
{
  if (*gate != want) return;
  __shared__ __align__(16) char lds[32 * 136];
  const int rt = blockIdx.x, n = blockIdx.y;
  const int t = threadIdx.x, wid = t >> 6, lane = t & 63, quad = lane >> 4, l16 = lane & 15;
  const int rw = rt * 64 + wid * 16;
  const TW*  wvn = WV   + (size_t)n * 262144;
  const bf16* sn = Sbuf + (size_t)n * 1048576;
  floatx4 acc[4];
  #pragma unroll
  for (int ft = 0; ft < 4; ft++) acc[ft] = (floatx4){0.f, 0.f, 0.f, 0.f};
  const int row = t >> 3, f8 = (t & 7) * 8;
  for (int kb = 0; kb < 4096; kb += 32) {
    { // stage chunk: lds[row][f] = WV[kb+row][f]  (bf16)
      const TW* src = wvn + (size_t)(kb + row) * 64 + f8;
      short sv[8];
      if constexpr (sizeof(TW) == 2) {
        short8 v = ld_g8((const bf16*)src);
        #pragma unroll
        for (int j = 0; j < 8; j++) sv[j] = v[j];
      } else {
        float4 a = *reinterpret_cast<const float4*>(src);
        float4 b = *reinterpret_cast<const float4*>(src + 4);
        sv[0]=bfs(a.x); sv[1]=bfs(a.y); sv[2]=bfs(a.z); sv[3]=bfs(a.w);
        sv[4]=bfs(b.x); sv[5]=bfs(b.y); sv[6]=bfs(b.z); sv[7]=bfs(b.w);
      }
      short* dst = reinterpret_cast<short*>(lds + row*136 + f8*2);
      s16x4 lo = {sv[0],sv[1],sv[2],sv[3]}, hi = {sv[4],sv[5],sv[6],sv[7]};
      *reinterpret_cast<s16x4*>(dst)     = lo;
      *reinterpret_cast<s16x4*>(dst + 4) = hi;
    }
    __syncthreads();
    short8 af = ld_g8(sn + (size_t)(rw + l16) * 4096 + kb + quad*8);
    #pragma unroll
    for (int ft = 0; ft < 4; ft++) {
      short8 bfv;
      #pragma unroll
      for (int j = 0; j < 8; j++)
        bfv[j] = *reinterpret_cast<const short*>(
            lds + (quad*8 + j)*136 + (ft*16 + l16)*2);
      acc[ft] = mfma16(af, bfv, acc[ft]);
    }
    __syncthreads();
  }
  #pragma unroll
  for (int ft = 0; ft < 4; ft++)
    #pragma unroll
    for (int reg = 0; reg < 4; reg++)
      zbb[(size_t)(rw + quad*4 + reg) * 512 + n*64 + ft*16 + l16] =
          __float2bfloat16(acc[ft][reg]);
}

extern "C" void kernel_launch(void* const* d_in, const int* in_sizes, int n_in,
                              void* d_out, int out_size, void* d_ws, size_t ws_size,
                              hipStream_t stream)
{
  (void)in_sizes; (void)n_in; (void)out_size; (void)ws_size;
  // Workspace (bytes), ~21 MB total:
  //   flag [0,4); tproj bf16 [256, 1310976); tbsbf [1310976, 1343744)
  //   s1t bf16 [1343744, 3440896); zbb bf16 [3440896, 3703040)
  //   Sbuf bf16 [4194304, 20971520)   (8 n x 256 r x 4096)
  char* wsb = (char*)d_ws;
  int*  flag  = (int*)wsb;
  bf16* tproj = (bf16*)(wsb + 256);
  bf16* tbsbf = (bf16*)(wsb + 1310976);
  bf16* s1t   = (bf16*)(wsb + 1343744);
  bf16* zbb   = (bf16*)(wsb + 3440896);
  bf16* Sbuf  = (bf16*)(wsb + 4194304);
  const long TE = 131072;

  dtype_probe<<<1, 64, 0, stream>>>((const unsigned*)d_in[0], flag);

  proj_kern<bf16><<<dim3(1,4,40), 256, 0, stream>>>(
      flag, 1, (const bf16*)d_in[0],
      (const bf16*)d_in[1], (const bf16*)d_in[2], (const bf16*)d_in[3], (const bf16*)d_in[4],
      (const bf16*)d_in[5], (const bf16*)d_in[6], (const bf16*)d_in[7], (const bf16*)d_in[8],
      (const bf16*)d_in[9], (const bf16*)d_in[10], tproj);
  proj_kern<float><<<dim3(1,4,40), 256, 0, stream>>>(
      flag, 0, (const float*)d_in[0],
      (const float*)d_in[1], (const float*)d_in[2], (const float*)d_in[3], (const float*)d_in[4],
      (const float*)d_in[5], (const float*)d_in[6], (const float*)d_in[7], (const float*)d_in[8],
      (const float*)d_in[9], (const float*)d_in[10], tproj);
  tbs_kern<<<64, 256, 0, stream>>>(tproj + 1*TE, tbsbf);
  s1t_mfma<bf16><<<dim3(64,4), 256, 0, stream>>>(
      flag, 1, tproj + 2*TE, (const bf16*)d_in[12], s1t);
  s1t_mfma<float><<<dim3(64,4), 256, 0, stream>>>(
      flag, 0, tproj + 2*TE, (const float*)d_in[12], s1t);
  tri_attn<<<2048, 256, 0, stream>>>(
      tproj, tbsbf, s1t, tproj + 3*TE, tproj + 4*TE, Sbuf);
  z_kern<bf16><<<dim3(4,8), 256, 0, stream>>>(
      flag, 1, Sbuf, (const bf16*)d_in[11], zbb);
  z_kern<float><<<dim3(4,8), 256, 0, stream>>>(
      flag, 0, Sbuf, (const float*)d_in[11], zbb);
  gemm_tile<bf16, bf16, bf16, true><<<dim3(8,4), 256, 0, stream>>>(
      flag, 1, zbb, (const bf16*)d_in[13], (bf16*)d_out, (const bf16*)d_in[14],
      512, 512, 512, 512);
  gemm_tile<bf16, float, float, true><<<dim3(8,4), 256, 0, stream>>>(
      flag, 0, zbb, (const float*)d_in[13], (float*)d_out, (const float*)d_in[14],
      512, 512, 512, 512);
}

// Round 10
// 280.466 us; speedup vs baseline: 1.3095x; 1.3095x over previous
//
#include <hip/hip_runtime.h>
#include <hip/hip_bf16.h>

// TrittentionCube on MI355X. B=1, P=256, D=512, N=8, H=64. Round 10:
//  - z_kern split-K (ks=8 -> 256 blocks; was 32 blocks @1.4% occupancy, 130us)
//    writing fp32 partials; zred sums partials -> bf16 zbb.
//  - ks/zpart placement chosen at launch from ws_size (deterministic, graph-safe).
// Everything else as round 9 (tri_attn ends at S'=S/Z in Sbuf).

typedef __hip_bfloat16 bf16;
typedef __attribute__((ext_vector_type(8))) short short8;
typedef __attribute__((ext_vector_type(4))) short s16x4;
typedef __attribute__((ext_vector_type(4))) float floatx4;

__device__ __forceinline__ float ldf(const float* p){ return *p; }
__device__ __forceinline__ float ldf(const bf16* p){ return __bfloat162float(*p); }
__device__ __forceinline__ void  stf(float* p, float v){ *p = v; }
__device__ __forceinline__ void  stf(bf16*  p, float v){ *p = __float2bfloat16(v); }

__device__ __forceinline__ floatx4 mfma16(short8 a, short8 b, floatx4 c){
  return __builtin_amdgcn_mfma_f32_16x16x32_bf16(a, b, c, 0, 0, 0);
}
__device__ __forceinline__ short8 ld_g8(const bf16* p){
  return *reinterpret_cast<const short8*>(p);
}
__device__ __forceinline__ short bfs(float x){
  bf16 v = __float2bfloat16(x);
  return *reinterpret_cast<short*>(&v);
}

// Input-dtype probe: flag=1 if bf16, 0 if fp32.
__global__ void dtype_probe(const unsigned* __restrict__ x, int* __restrict__ flag)
{
  int t = threadIdx.x;              // 64 threads
  int cnt = 0;
  #pragma unroll
  for (int k = 0; k < 4; k++) {
    unsigned w = x[t*4 + k];
    unsigned lo = w & 0xFFFFu;
    unsigned e  = (lo >> 7) & 0xFFu;
    if (lo == 0u || (e >= 90u && e <= 145u)) cnt++;
  }
  #pragma unroll
  for (int off = 32; off; off >>= 1) cnt += __shfl_down(cnt, off);
  if (t == 0) *flag = (cnt >= 160) ? 1 : 0;
}

// Fused 5-projection kernel: t_j[p,n,h] = x @ W_j[n] + b_j[n].
// j<3: [p][n*64+h]; j>=3: transposed [n][h][p] (tdT/teT for MFMA B-frags).
template<typename TI>
__global__ __launch_bounds__(256) void proj_kern(
    const int* __restrict__ gate, int want, const TI* __restrict__ x,
    const TI* __restrict__ W0, const TI* __restrict__ b0,
    const TI* __restrict__ W1, const TI* __restrict__ b1,
    const TI* __restrict__ W2, const TI* __restrict__ b2,
    const TI* __restrict__ W3, const TI* __restrict__ b3,
    const TI* __restrict__ W4, const TI* __restrict__ b4,
    bf16* __restrict__ tproj)
{
  if (*gate != want) return;
  const TI* Ws[5] = {W0, W1, W2, W3, W4};
  const TI* bs[5] = {b0, b1, b2, b3, b4};
  const int bz = blockIdx.z, j = bz >> 3, n = bz & 7;
  const TI* B    = Ws[j] + (size_t)n * 32768;
  const TI* bias = bs[j] + n * 64;
  bf16* out = tproj + (size_t)j * 131072;
  const int m0 = blockIdx.y * 64;
  __shared__ float As[16][68];
  __shared__ float Bs[16][68];
  const int t = threadIdx.x, tx = t & 15, ty = t >> 4;
  float acc[4][4] = {};
  for (int k0 = 0; k0 < 512; k0 += 16) {
    { int m = t >> 2, kk = (t & 3) * 4;
      const TI* ap = x + (size_t)(m0 + m) * 512 + (k0 + kk);
      float a0 = ldf(ap+0), a1 = ldf(ap+1), a2 = ldf(ap+2), a3 = ldf(ap+3);
      As[kk+0][m] = a0; As[kk+1][m] = a1; As[kk+2][m] = a2; As[kk+3][m] = a3; }
    { int kk = t >> 4, nn = (t & 15) * 4;
      const TI* bp = B + (size_t)(k0 + kk) * 64 + nn;
      Bs[kk][nn+0] = ldf(bp+0); Bs[kk][nn+1] = ldf(bp+1);
      Bs[kk][nn+2] = ldf(bp+2); Bs[kk][nn+3] = ldf(bp+3); }
    __syncthreads();
    #pragma unroll
    for (int kk = 0; kk < 16; kk++) {
      float4 a4 = *reinterpret_cast<const float4*>(&As[kk][ty*4]);
      float4 b4 = *reinterpret_cast<const float4*>(&Bs[kk][tx*4]);
      float av[4] = {a4.x,a4.y,a4.z,a4.w}, bv[4] = {b4.x,b4.y,b4.z,b4.w};
      #pragma unroll
      for (int im = 0; im < 4; im++)
        #pragma unroll
        for (int in = 0; in < 4; in++) acc[im][in] += av[im] * bv[in];
    }
    __syncthreads();
  }
  #pragma unroll
  for (int im = 0; im < 4; im++)
    #pragma unroll
    for (int in = 0; in < 4; in++) {
      float v = acc[im][in] + ldf(bias + tx*4 + in);
      int p = m0 + ty*4 + im, h = tx*4 + in;
      if (j < 3) out[(size_t)p * 512 + n*64 + h] = __float2bfloat16(v);
      else       out[(size_t)n * 16384 + (size_t)h * 256 + p] = __float2bfloat16(v);
    }
}

// MFMA s1t: s1t[r][(i,j)] = sum_{n,k} tc[r][(n,k)] * W_K[n][i][j][k].
template<typename TW>
__global__ __launch_bounds__(256) void s1t_mfma(
    const int* __restrict__ gate, int want,
    const bf16* __restrict__ tc, const TW* __restrict__ WK, bf16* __restrict__ s1t)
{
  if (*gate != want) return;
  const int i = blockIdx.x;
  const int t = threadIdx.x, wid = t >> 6, lane = t & 63, quad = lane >> 4, l16 = lane & 15;
  const int rw = blockIdx.y * 64 + wid * 16;
  floatx4 acc[4];
  #pragma unroll
  for (int jt = 0; jt < 4; jt++) acc[jt] = (floatx4){0.f, 0.f, 0.f, 0.f};
  for (int kc = 0; kc < 16; kc++) {
    short8 af = ld_g8(tc + (size_t)(rw + l16) * 512 + kc*32 + quad*8);
    const int n = kc >> 1, kk = (kc & 1) * 32 + quad * 8;
    #pragma unroll
    for (int jt = 0; jt < 4; jt++) {
      const TW* bp = WK + ((size_t)(n*64 + i) * 64 + jt*16 + l16) * 64 + kk;
      short8 bf;
      if constexpr (sizeof(TW) == 2) {
        bf = ld_g8((const bf16*)bp);
      } else {
        float4 x0 = *reinterpret_cast<const float4*>(bp);
        float4 x1 = *reinterpret_cast<const float4*>(bp + 4);
        bf[0]=bfs(x0.x); bf[1]=bfs(x0.y); bf[2]=bfs(x0.z); bf[3]=bfs(x0.w);
        bf[4]=bfs(x1.x); bf[5]=bfs(x1.y); bf[6]=bfs(x1.z); bf[7]=bfs(x1.w);
      }
      acc[jt] = mfma16(af, bf, acc[jt]);
    }
  }
  #pragma unroll
  for (int jt = 0; jt < 4; jt++)
    #pragma unroll
    for (int reg = 0; reg < 4; reg++)
      s1t[(size_t)(rw + quad*4 + reg) * 4096 + i*64 + jt*16 + l16] =
          __float2bfloat16(acc[jt][reg]);
}

// Generic 64x64-tile GEMM (final out only).
template<typename TA, typename TB, typename TC, bool BIAS>
__global__ __launch_bounds__(256) void gemm_tile(
    const int* __restrict__ gate, int want,
    const TA* __restrict__ A, const TB* __restrict__ B, TC* __restrict__ C,
    const TB* __restrict__ bias,
    int Ncols, int K, int lda, int ldc)
{
  if (*gate != want) return;
  const int m0 = blockIdx.y * 64, n0 = blockIdx.x * 64;
  __shared__ float As[16][68];
  __shared__ float Bs[16][68];
  const int t = threadIdx.x, tx = t & 15, ty = t >> 4;
  float acc[4][4] = {};
  for (int k0 = 0; k0 < K; k0 += 16) {
    { int m = t >> 2, kk = (t & 3) * 4;
      const TA* ap = A + (size_t)(m0 + m) * lda + (k0 + kk);
      float a0 = ldf(ap+0), a1 = ldf(ap+1), a2 = ldf(ap+2), a3 = ldf(ap+3);
      As[kk+0][m] = a0; As[kk+1][m] = a1; As[kk+2][m] = a2; As[kk+3][m] = a3; }
    { int kk = t >> 4, nn = (t & 15) * 4;
      const TB* bp = B + (size_t)(k0 + kk) * Ncols + (n0 + nn);
      Bs[kk][nn+0] = ldf(bp+0); Bs[kk][nn+1] = ldf(bp+1);
      Bs[kk][nn+2] = ldf(bp+2); Bs[kk][nn+3] = ldf(bp+3); }
    __syncthreads();
    #pragma unroll
    for (int kk = 0; kk < 16; kk++) {
      float4 a4 = *reinterpret_cast<const float4*>(&As[kk][ty*4]);
      float4 b4 = *reinterpret_cast<const float4*>(&Bs[kk][tx*4]);
      float av[4] = {a4.x,a4.y,a4.z,a4.w}, bv[4] = {b4.x,b4.y,b4.z,b4.w};
      #pragma unroll
      for (int im = 0; im < 4; im++)
        #pragma unroll
        for (int in = 0; in < 4; in++) acc[im][in] += av[im] * bv[in];
    }
    __syncthreads();
  }
  #pragma unroll
  for (int im = 0; im < 4; im++) {
    TC* cp = C + (size_t)(m0 + ty*4 + im) * ldc + n0 + tx*4;
    #pragma unroll
    for (int in = 0; in < 4; in++) {
      float v = acc[im][in];
      if constexpr (BIAS) v += ldf(bias + n0 + tx*4 + in);
      stf(cp + in, v);
    }
  }
}

// tbs[q][j] = (1/64) * sum_n tb[q][n][j]  -> bf16 [q][64]
__global__ __launch_bounds__(256) void tbs_kern(const bf16* __restrict__ tb,
                                                bf16* __restrict__ tbsbf)
{
  int t = blockIdx.x * 256 + threadIdx.x;
  int q = t >> 6, j = t & 63;
  float s = 0.f;
  #pragma unroll
  for (int n = 0; n < 8; n++) s += ldf(tb + q*512 + n*64 + j);
  tbsbf[t] = __float2bfloat16(s * 0.015625f);
}

// Per-(n,r) MFMA attention -> S' = S/Z written to Sbuf (no W_V here).
// LDS 53760 B: [0,34816) c [256][136 B] / Tt [64][528 B]; [34816,53248) Ew
// [64][72 B] x4 waves; [53248,53760) scr. p-tiles interleaved (i = pt*4+wid).
__global__ __launch_bounds__(256) void tri_attn(
    const bf16* __restrict__ ta,     // [p][n*64+h]
    const bf16* __restrict__ tbsbf,  // [q][64]
    const bf16* __restrict__ s1t,    // [r][i*64+j]
    const bf16* __restrict__ tdT,    // [n][h][p]
    const bf16* __restrict__ teT,    // [n][g][q]
    bf16* __restrict__ Sbuf)         // [n][r][h*64+g]
{
  __shared__ __align__(16) char smb[53760];
  const int bx = blockIdx.x;
  const int n = bx & 7;               // n -> XCD affinity
  const int r = 255 - (bx >> 3);      // big-r first
  const int t = threadIdx.x;
  const int wid = t >> 6, lane = t & 63, quad = lane >> 4, l16 = lane & 15;
  bf16* srow = Sbuf + (size_t)n * 1048576 + (size_t)r * 4096;
  if (r < 2) {                        // no valid (p<q<r): S' = 0 (z=0 downstream)
    short8 zz = (short8){0,0,0,0,0,0,0,0};
    reinterpret_cast<short8*>(srow)[t]       = zz;
    reinterpret_cast<short8*>(srow)[t + 256] = zz;
    return;
  }

  // ---- Phase 1: c[q][i] = tbs[q,:]·s1t[r][i,:]  (rows q<1 or q>=r zeroed)
  {
    const bf16* s1r = s1t + (size_t)r * 4096;
    short8 bfr[4][2];
    #pragma unroll
    for (int it = 0; it < 4; it++)
      #pragma unroll
      for (int kc = 0; kc < 2; kc++)
        bfr[it][kc] = ld_g8(s1r + (it*16 + l16)*64 + kc*32 + quad*8);
    #pragma unroll
    for (int qt = 0; qt < 4; qt++) {
      const int q0 = wid * 64 + qt * 16;
      short8 af0 = ld_g8(tbsbf + (q0 + l16)*64 + quad*8);
      short8 af1 = ld_g8(tbsbf + (q0 + l16)*64 + 32 + quad*8);
      #pragma unroll
      for (int it = 0; it < 4; it++) {
        floatx4 acc = {0.f, 0.f, 0.f, 0.f};
        acc = mfma16(af0, bfr[it][0], acc);
        acc = mfma16(af1, bfr[it][1], acc);
        #pragma unroll
        for (int reg = 0; reg < 4; reg++) {
          int q = q0 + quad*4 + reg;
          float v = (q >= 1 && q < r) ? acc[reg] : 0.f;
          *reinterpret_cast<bf16*>(smb + q*136 + (it*16 + l16)*2) = __float2bfloat16(v);
        }
      }
    }
  }
  short8 taf[4][2];
  #pragma unroll
  for (int pt = 0; pt < 4; pt++)
    #pragma unroll
    for (int kc = 0; kc < 2; kc++)
      taf[pt][kc] = ld_g8(ta + (size_t)((pt*4 + wid)*16 + l16)*512 + n*64
                             + kc*32 + quad*8);
  __syncthreads();                    // c visible

  // ---- Main loop: E chunk + T accumulate; 3-case wave-uniform masking
  floatx4 Tacc[4][4];
  #pragma unroll
  for (int pt = 0; pt < 4; pt++)
    #pragma unroll
    for (int gt = 0; gt < 4; gt++) Tacc[pt][gt] = (floatx4){0.f, 0.f, 0.f, 0.f};
  float Zp = 0.f;
  char* EwB = smb + 34816 + wid * 4608;          // [64][72 B] bf16 per wave
  const int nch = ((r - 1) >> 5) + 1;
  for (int ch = 0; ch < nch; ch++) {
    const int qc = ch * 32;
    if (qc + 31 <= wid * 16) continue;  // all this wave's tiles dead
    short8 cfr[2][2];
    #pragma unroll
    for (int qt2 = 0; qt2 < 2; qt2++)
      #pragma unroll
      for (int kc = 0; kc < 2; kc++)
        cfr[qt2][kc] = *reinterpret_cast<const short8*>(
            smb + (qc + qt2*16 + l16)*136 + (kc*32 + quad*8)*2);
    #pragma unroll
    for (int pt = 0; pt < 4; pt++) {
      const int ptb = (pt*4 + wid) * 16;
      if (ptb < qc + 31) {            // wave-uniform: tile has live (p,q)
        #pragma unroll
        for (int qt2 = 0; qt2 < 2; qt2++) {
          const int qh = qc + qt2*16;
          char* erow0 = EwB + (pt*16 + quad*4)*72 + (qt2*16 + l16)*2;
          if (qh + 15 <= ptb) {                   // fully-masked half-tile
            #pragma unroll
            for (int reg = 0; reg < 4; reg++)
              *reinterpret_cast<bf16*>(erow0 + reg*72) = __float2bfloat16(0.f);
          } else {
            floatx4 acc = {0.f, 0.f, 0.f, 0.f};
            acc = mfma16(taf[pt][0], cfr[qt2][0], acc);
            acc = mfma16(taf[pt][1], cfr[qt2][1], acc);
            if (qh >= ptb + 16 && qh + 15 < r) {  // interior: no per-lane mask
              #pragma unroll
              for (int reg = 0; reg < 4; reg++) {
                float e = __expf(acc[reg]);
                Zp += e;
                *reinterpret_cast<bf16*>(erow0 + reg*72) = __float2bfloat16(e);
              }
            } else {                              // diagonal / last chunk
              #pragma unroll
              for (int reg = 0; reg < 4; reg++) {
                int p = ptb + quad*4 + reg;
                int q = qh + l16;
                float e = (p < q && q < r) ? __expf(acc[reg]) : 0.f;
                Zp += e;
                *reinterpret_cast<bf16*>(erow0 + reg*72) = __float2bfloat16(e);
              }
            }
          }
        }
      }
    }
    short8 tef[4];
    #pragma unroll
    for (int gt = 0; gt < 4; gt++)
      tef[gt] = ld_g8(teT + (size_t)n*16384 + (gt*16 + l16)*256 + qc + quad*8);
    #pragma unroll
    for (int pt = 0; pt < 4; pt++) {
      if ((pt*4 + wid)*16 < qc + 31) {
        short8 ef = *reinterpret_cast<const short8*>(EwB + (pt*16 + l16)*72 + quad*16);
        #pragma unroll
        for (int gt = 0; gt < 4; gt++)
          Tacc[pt][gt] = mfma16(ef, tef[gt], Tacc[pt][gt]);
      }
    }
  }
  #pragma unroll
  for (int off = 32; off; off >>= 1) Zp += __shfl_down(Zp, off);
  float* scr = reinterpret_cast<float*>(smb + 53248);
  if (lane == 0) scr[wid] = Zp;
  __syncthreads();                    // closes all c reads; Z visible
  const float rinv = 1.f / (scr[0] + scr[1] + scr[2] + scr[3]);

  // ---- Tt[g][p] (bf16, stride 528 B) over dead c region
  #pragma unroll
  for (int pt = 0; pt < 4; pt++)
    #pragma unroll
    for (int gt = 0; gt < 4; gt++)
      #pragma unroll
      for (int reg = 0; reg < 4; reg++) {
        int g = gt*16 + l16;
        int p = (pt*4 + wid)*16 + quad*4 + reg;
        *reinterpret_cast<bf16*>(smb + g*528 + p*2) = __float2bfloat16(Tacc[pt][gt][reg]);
      }
  __syncthreads();

  // ---- S[g][h] = T^T·tdT (K=256); store S' = S*rinv to Sbuf[h*64+g]
  {
    short8 Taf[8];
    #pragma unroll
    for (int kc = 0; kc < 8; kc++)
      Taf[kc] = *reinterpret_cast<const short8*>(
          smb + (wid*16 + l16)*528 + (kc*32 + quad*8)*2);
    #pragma unroll
    for (int ht = 0; ht < 4; ht++) {
      floatx4 acc = {0.f, 0.f, 0.f, 0.f};
      #pragma unroll
      for (int kc = 0; kc < 8; kc++) {
        short8 bfragd = ld_g8(tdT + (size_t)n*16384 + (ht*16 + l16)*256 + kc*32 + quad*8);
        acc = mfma16(Taf[kc], bfragd, acc);
      }
      #pragma unroll
      for (int reg = 0; reg < 4; reg++) {
        int g = wid*16 + quad*4 + reg, h = ht*16 + l16;
        srow[h*64 + g] = __float2bfloat16(acc[reg] * rinv);
      }
    }
  }
}

// z_kern split-K: zpart[ks][r][n*64+f] = sum_{k in slice} S'[n][r][k]*WV[n][k][f].
// Grid (rt=4, n=8, ks); slice = 4096/ks. W_V chunk staged in LDS [32][136 B].
template<typename TW>
__global__ __launch_bounds__(256) void z_kern(
    const int* __restrict__ gate, int want,
    const bf16* __restrict__ Sbuf, const TW* __restrict__ WV,
    float* __restrict__ zpart, int kslice)
{
  if (*gate != want) return;
  __shared__ __align__(16) char lds[32 * 136];
  const int rt = blockIdx.x, n = blockIdx.y, ks = blockIdx.z;
  const int t = threadIdx.x, wid = t >> 6, lane = t & 63, quad = lane >> 4, l16 = lane & 15;
  const int rw = rt * 64 + wid * 16;
  const int k0 = ks * kslice;
  const TW*  wvn = WV   + (size_t)n * 262144;
  const bf16* sn = Sbuf + (size_t)n * 1048576;
  floatx4 acc[4];
  #pragma unroll
  for (int ft = 0; ft < 4; ft++) acc[ft] = (floatx4){0.f, 0.f, 0.f, 0.f};
  const int row = t >> 3, f8 = (t & 7) * 8;
  for (int kb = k0; kb < k0 + kslice; kb += 32) {
    { // stage chunk: lds[row][f] = WV[kb+row][f]  (bf16)
      const TW* src = wvn + (size_t)(kb + row) * 64 + f8;
      short sv[8];
      if constexpr (sizeof(TW) == 2) {
        short8 v = ld_g8((const bf16*)src);
        #pragma unroll
        for (int j = 0; j < 8; j++) sv[j] = v[j];
      } else {
        float4 a = *reinterpret_cast<const float4*>(src);
        float4 b = *reinterpret_cast<const float4*>(src + 4);
        sv[0]=bfs(a.x); sv[1]=bfs(a.y); sv[2]=bfs(a.z); sv[3]=bfs(a.w);
        sv[4]=bfs(b.x); sv[5]=bfs(b.y); sv[6]=bfs(b.z); sv[7]=bfs(b.w);
      }
      short* dst = reinterpret_cast<short*>(lds + row*136 + f8*2);
      s16x4 lo = {sv[0],sv[1],sv[2],sv[3]}, hi = {sv[4],sv[5],sv[6],sv[7]};
      *reinterpret_cast<s16x4*>(dst)     = lo;
      *reinterpret_cast<s16x4*>(dst + 4) = hi;
    }
    __syncthreads();
    short8 af = ld_g8(sn + (size_t)(rw + l16) * 4096 + kb + quad*8);
    #pragma unroll
    for (int ft = 0; ft < 4; ft++) {
      short8 bfv;
      #pragma unroll
      for (int j = 0; j < 8; j++)
        bfv[j] = *reinterpret_cast<const short*>(
            lds + (quad*8 + j)*136 + (ft*16 + l16)*2);
      acc[ft] = mfma16(af, bfv, acc[ft]);
    }
    __syncthreads();
  }
  float* zp = zpart + (size_t)ks * 131072;
  #pragma unroll
  for (int ft = 0; ft < 4; ft++)
    #pragma unroll
    for (int reg = 0; reg < 4; reg++)
      zp[(size_t)(rw + quad*4 + reg) * 512 + n*64 + ft*16 + l16] = acc[ft][reg];
}

// zred: zbb[idx] = bf16( sum_ks zpart[ks][idx] ), idx over 256*512.
__global__ __launch_bounds__(256) void zred_kern(
    const float* __restrict__ zpart, bf16* __restrict__ zbb, int ks)
{
  int idx = blockIdx.x * 256 + threadIdx.x;   // 512 blocks
  float s = 0.f;
  for (int k = 0; k < ks; k++) s += zpart[(size_t)k * 131072 + idx];
  zbb[idx] = __float2bfloat16(s);
}

extern "C" void kernel_launch(void* const* d_in, const int* in_sizes, int n_in,
                              void* d_out, int out_size, void* d_ws, size_t ws_size,
                              hipStream_t stream)
{
  (void)in_sizes; (void)n_in; (void)out_size;
  // Workspace (bytes):
  //   flag [0,4); tproj bf16 [256, 1310976); tbsbf [1310976, 1343744)
  //   s1t bf16 [1343744, 3440896); zbb bf16 [3440896, 3703040)
  //   Sbuf bf16 [4194304, 20971520)
  //   zpart fp32: ks=8 @ [20971520, 25165824) if ws allows, else ks=2 over dead
  //   s1t region [1343744, 2392064) (s1t dead after tri_attn).
  char* wsb = (char*)d_ws;
  int*  flag  = (int*)wsb;
  bf16* tproj = (bf16*)(wsb + 256);
  bf16* tbsbf = (bf16*)(wsb + 1310976);
  bf16* s1t   = (bf16*)(wsb + 1343744);
  bf16* zbb   = (bf16*)(wsb + 3440896);
  bf16* Sbuf  = (bf16*)(wsb + 4194304);
  const long TE = 131072;
  const bool bigws = (ws_size == 0) || (ws_size >= 25165824);   // ws_size const per session
  const int  ks     = bigws ? 8 : 2;
  const int  kslice = 4096 / ks;
  float* zpart = (float*)(bigws ? (wsb + 20971520) : (wsb + 1343744));

  dtype_probe<<<1, 64, 0, stream>>>((const unsigned*)d_in[0], flag);

  proj_kern<bf16><<<dim3(1,4,40), 256, 0, stream>>>(
      flag, 1, (const bf16*)d_in[0],
      (const bf16*)d_in[1], (const bf16*)d_in[2], (const bf16*)d_in[3], (const bf16*)d_in[4],
      (const bf16*)d_in[5], (const bf16*)d_in[6], (const bf16*)d_in[7], (const bf16*)d_in[8],
      (const bf16*)d_in[9], (const bf16*)d_in[10], tproj);
  proj_kern<float><<<dim3(1,4,40), 256, 0, stream>>>(
      flag, 0, (const float*)d_in[0],
      (const float*)d_in[1], (const float*)d_in[2], (const float*)d_in[3], (const float*)d_in[4],
      (const float*)d_in[5], (const float*)d_in[6], (const float*)d_in[7], (const float*)d_in[8],
      (const float*)d_in[9], (const float*)d_in[10], tproj);
  tbs_kern<<<64, 256, 0, stream>>>(tproj + 1*TE, tbsbf);
  s1t_mfma<bf16><<<dim3(64,4), 256, 0, stream>>>(
      flag, 1, tproj + 2*TE, (const bf16*)d_in[12], s1t);
  s1t_mfma<float><<<dim3(64,4), 256, 0, stream>>>(
      flag, 0, tproj + 2*TE, (const float*)d_in[12], s1t);
  tri_attn<<<2048, 256, 0, stream>>>(
      tproj, tbsbf, s1t, tproj + 3*TE, tproj + 4*TE, Sbuf);
  z_kern<bf16><<<dim3(4,8,ks), 256, 0, stream>>>(
      flag, 1, Sbuf, (const bf16*)d_in[11], zpart, kslice);
  z_kern<float><<<dim3(4,8,ks), 256, 0, stream>>>(
      flag, 0, Sbuf, (const float*)d_in[11], zpart, kslice);
  zred_kern<<<512, 256, 0, stream>>>(zpart, zbb, ks);
  gemm_tile<bf16, bf16, bf16, true><<<dim3(8,4), 256, 0, stream>>>(
      flag, 1, zbb, (const bf16*)d_in[13], (bf16*)d_out, (const bf16*)d_in[14],
      512, 512, 512, 512);
  gemm_tile<bf16, float, float, true><<<dim3(8,4), 256, 0, stream>>>(
      flag, 0, zbb, (const float*)d_in[13], (float*)d_out, (const float*)d_in[14],
      512, 512, 512, 512);
}